// Round 1
// baseline (6805.531 us; speedup 1.0000x reference)
//
#include <hip/hip_runtime.h>
#include <cstdint>

// ---------------------------------------------------------------------------
// LAC block, fp32 reference-faithful implementation (round 0: correctness).
// Shapes: B=32, C=1, H=1024, W=512, DH=1024, N=4 heads, D=64.
// Workspace layout (floats):
//   X    = ws + 0          : 16,777,216   running activation (B,H,W)
//   B1   = ws + 16,777,216 : 16,777,216   ping buffer (chunked LFFN T1/T3)
//   B2   = ws + 33,554,432 : 16,777,216   pong buffer (chunked LFFN T2)
//   MHLA overlays (B1/B2 dead between LFFNs):
//     Q  = B1 + 0, K = B1 + 8,388,608, V = B2 + 0
//     W2 = B2 + 8,388,608 (32*256*512), Bm = B2 + 12,582,912 (32*4*64*64)
//     wpack = B2 + 13,107,200 (3*512*256), stats = B2 + 13,500,416
// Total: 50,331,648 floats = 201.3 MB of d_ws.
// ---------------------------------------------------------------------------

static __device__ __forceinline__ float sigm(float x) { return 1.0f / (1.0f + expf(-x)); }

// C[M,N] = [swish]( alpha * A@B [+ bias(col)] [+ res] ); optional batch (z) strides.
__global__ __launch_bounds__(256) void gemm_f32(
    const float* __restrict__ A, const float* __restrict__ B, float* __restrict__ C,
    const float* __restrict__ res, const float* __restrict__ bias,
    int N, int K, float alpha, int do_swish,
    long long bsA, long long bsB, long long bsC)
{
    const int bz = blockIdx.z;
    A += (long long)bz * bsA;
    B += (long long)bz * bsB;
    C += (long long)bz * bsC;
    const float* resp = res ? res + (long long)bz * bsC : nullptr;

    __shared__ float As[16][64];   // As[k][m]
    __shared__ float Bs[16][64];   // Bs[k][n]

    const int bm = blockIdx.y * 64;
    const int bn = blockIdx.x * 64;
    const int tid = threadIdx.x;
    const int tx = tid & 15, ty = tid >> 4;

    float acc[4][4] = {};

    const int am = tid >> 2, ak = (tid & 3) << 2;   // A tile: 64 rows x 16 k
    const int bk = tid >> 4, bnn = (tid & 15) << 2; // B tile: 16 k x 64 n

    for (int k0 = 0; k0 < K; k0 += 16) {
        float4 a4 = *(const float4*)(A + (long long)(bm + am) * K + (k0 + ak));
        As[ak + 0][am] = a4.x; As[ak + 1][am] = a4.y;
        As[ak + 2][am] = a4.z; As[ak + 3][am] = a4.w;
        *(float4*)(&Bs[bk][bnn]) = *(const float4*)(B + (long long)(k0 + bk) * N + (bn + bnn));
        __syncthreads();
#pragma unroll
        for (int k = 0; k < 16; ++k) {
            const float4 av = *(const float4*)(&As[k][ty << 2]);
            const float4 bv = *(const float4*)(&Bs[k][tx << 2]);
            float a[4] = {av.x, av.y, av.z, av.w};
            float b[4] = {bv.x, bv.y, bv.z, bv.w};
#pragma unroll
            for (int i = 0; i < 4; ++i)
#pragma unroll
                for (int j = 0; j < 4; ++j)
                    acc[i][j] = fmaf(a[i], b[j], acc[i][j]);
        }
        __syncthreads();
    }

#pragma unroll
    for (int i = 0; i < 4; ++i) {
        const long long cidx = (long long)(bm + (ty << 2) + i) * N + bn + (tx << 2);
        float v[4];
#pragma unroll
        for (int j = 0; j < 4; ++j) v[j] = alpha * acc[i][j];
        if (bias) {
#pragma unroll
            for (int j = 0; j < 4; ++j) v[j] += bias[bn + (tx << 2) + j];
        }
        if (resp) {
            const float4 r4 = *(const float4*)(resp + cidx);
            v[0] += r4.x; v[1] += r4.y; v[2] += r4.z; v[3] += r4.w;
        }
        if (do_swish) {
#pragma unroll
            for (int j = 0; j < 4; ++j) v[j] = v[j] * sigm(v[j]);
        }
        *(float4*)(C + cidx) = make_float4(v[0], v[1], v[2], v[3]);
    }
}

// wq/wk/wv (4,512,64) -> wpack[t][w][n*64+d] row-major (512 x 256) each.
__global__ void repack_qkv(const float* __restrict__ wq, const float* __restrict__ wk,
                           const float* __restrict__ wv, float* __restrict__ out)
{
    const int i = blockIdx.x * 256 + threadIdx.x;  // 0 .. 393215
    const int t = i >> 17;         // tensor (131072 each)
    const int r = i & 131071;
    const int w = r >> 8;
    const int c = r & 255;
    const float* src = (t == 0) ? wq : (t == 1) ? wk : wv;
    out[i] = src[(c >> 6) * 32768 + w * 64 + (c & 63)];
}

// Column softmax over H=1024 per (b, col) for Q and K, in place, with pre-scale.
// grid (32, 2), block 1024: tid -> col = tid&255, seg = tid>>8 (4-way H split).
__global__ __launch_bounds__(1024) void softmax_h(float* __restrict__ Q, float* __restrict__ Kt,
                                                  float scale_q, float scale_k)
{
    float* Xp = (blockIdx.y == 0) ? Q : Kt;
    const float sc = (blockIdx.y == 0) ? scale_q : scale_k;
    const int b = blockIdx.x;
    const int col = threadIdx.x & 255;
    const int seg = threadIdx.x >> 8;
    const long long base = (long long)b * 1024 * 256;
    __shared__ float red[4][256];

    float m = -1e30f;
    for (int h = seg * 256; h < seg * 256 + 256; ++h)
        m = fmaxf(m, Xp[base + (long long)h * 256 + col] * sc);
    red[seg][col] = m;
    __syncthreads();
    m = fmaxf(fmaxf(red[0][col], red[1][col]), fmaxf(red[2][col], red[3][col]));
    __syncthreads();

    float s = 0.0f;
    for (int h = seg * 256; h < seg * 256 + 256; ++h)
        s += expf(Xp[base + (long long)h * 256 + col] * sc - m);
    red[seg][col] = s;
    __syncthreads();
    s = red[0][col] + red[1][col] + red[2][col] + red[3][col];
    const float inv = 1.0f / s;

    for (int h = seg * 256; h < seg * 256 + 256; ++h) {
        const long long idx = base + (long long)h * 256 + col;
        Xp[idx] = expf(Xp[idx] * sc - m) * inv;
    }
}

// Bm[b,n,d,e] = sum_h Ksm[b,h,n,d] * V[b,h,n,e].  grid 128 = (b*4+n), block 256.
__global__ __launch_bounds__(256) void bm_kernel(const float* __restrict__ Ksm,
                                                 const float* __restrict__ V,
                                                 float* __restrict__ Bm)
{
    const int b = blockIdx.x >> 2, n = blockIdx.x & 3;
    const long long base = (long long)b * 1024 * 256 + n * 64;
    __shared__ float Ks[64][64];
    __shared__ float Vs[64][64];
    const int tid = threadIdx.x;
    const int d = tid & 63, eg = tid >> 6;   // eg*16 .. +15 e-values
    float acc[16] = {};

    for (int h0 = 0; h0 < 1024; h0 += 64) {
        const int cc = tid & 63;
        for (int r = 0; r < 16; ++r) {
            const int hh = (tid >> 6) * 16 + r;
            Ks[hh][cc] = Ksm[base + (long long)(h0 + hh) * 256 + cc];
            Vs[hh][cc] = V[base + (long long)(h0 + hh) * 256 + cc];
        }
        __syncthreads();
        for (int hh = 0; hh < 64; ++hh) {
            const float kd = Ks[hh][d];
#pragma unroll
            for (int j = 0; j < 16; ++j)
                acc[j] = fmaf(kd, Vs[hh][eg * 16 + j], acc[j]);
        }
        __syncthreads();
    }
    float* outp = Bm + (long long)(b * 4 + n) * 4096 + d * 64 + eg * 16;
    for (int j = 0; j < 16; ++j) outp[j] = acc[j];
}

// W2[b][n*64+d][w] = sum_e Bm[b,n,d,e] * wo[n*64+e][w].  grid 128 = (b*4+n).
__global__ __launch_bounds__(256) void w2_kernel(const float* __restrict__ Bm,
                                                 const float* __restrict__ wo,
                                                 float* __restrict__ W2)
{
    const int b = blockIdx.x >> 2, n = blockIdx.x & 3;
    __shared__ float BmT[64][64];  // BmT[e][d]
    __shared__ float Ws[64][64];   // Ws[e][w]
    const int tid = threadIdx.x;
    const float* bm = Bm + (long long)(b * 4 + n) * 4096;

    for (int r = 0; r < 16; ++r) {
        const int d2 = (tid >> 6) * 16 + r, e2 = tid & 63;
        BmT[e2][d2] = bm[d2 * 64 + e2];
    }
    __syncthreads();

    const int d = tid & 63, wg = tid >> 6;
    for (int w0 = 0; w0 < 512; w0 += 64) {
        for (int r = 0; r < 16; ++r) {
            const int e2 = (tid >> 6) * 16 + r, ww = tid & 63;
            Ws[e2][ww] = wo[(long long)(n * 64 + e2) * 512 + w0 + ww];
        }
        __syncthreads();
        float acc[16] = {};
        for (int e = 0; e < 64; ++e) {
            const float bv = BmT[e][d];
#pragma unroll
            for (int j = 0; j < 16; ++j)
                acc[j] = fmaf(bv, Ws[e][wg * 16 + j], acc[j]);
        }
        float* outp = W2 + (long long)b * 256 * 512 + (long long)(n * 64 + d) * 512 + w0 + wg * 16;
        for (int j = 0; j < 16; ++j) outp[j] = acc[j];
        __syncthreads();
    }
}

// Per-batch mean / rstd over 524288 elements. grid 32, block 1024.
__global__ __launch_bounds__(1024) void stats_kernel(const float* __restrict__ X,
                                                     float* __restrict__ stats)
{
    const int b = blockIdx.x;
    const float* p = X + (long long)b * 524288;
    float s = 0.0f, ss = 0.0f;
    for (int i = threadIdx.x; i < 524288; i += 1024) {
        const float v = p[i];
        s += v; ss += v * v;
    }
    __shared__ float rs[1024];
    __shared__ float rss[1024];
    rs[threadIdx.x] = s; rss[threadIdx.x] = ss;
    __syncthreads();
    for (int off = 512; off > 0; off >>= 1) {
        if (threadIdx.x < (unsigned)off) {
            rs[threadIdx.x] += rs[threadIdx.x + off];
            rss[threadIdx.x] += rss[threadIdx.x + off];
        }
        __syncthreads();
    }
    if (threadIdx.x == 0) {
        const float mu = rs[0] / 524288.0f;
        const float var = rss[0] / 524288.0f - mu * mu;
        stats[b * 2 + 0] = mu;
        stats[b * 2 + 1] = rsqrtf(var + 1e-5f);
    }
}

// Fused conv module: LN -> pw1 -> GLU(H) -> dwconv(1,3) -> dw2(C->2C)+fold ->
// BN -> swish -> pw2 -> residual add. grid 32*512 (b,hr), block 512 (w).
__global__ __launch_bounds__(512) void conv_kernel(
    float* __restrict__ X, const float* __restrict__ stats,
    const float* __restrict__ ln1_g, const float* __restrict__ ln1_b,
    const float* __restrict__ pw1_w, const float* __restrict__ pw1_b,
    const float* __restrict__ dw1_w, const float* __restrict__ dw1_b,
    const float* __restrict__ dw2_w, const float* __restrict__ dw2_b,
    const float* __restrict__ bn_g, const float* __restrict__ bn_b,
    const float* __restrict__ bn_m, const float* __restrict__ bn_v,
    const float* __restrict__ pw2_w, const float* __restrict__ pw2_b)
{
    const int b = blockIdx.x >> 9;
    const int hr = blockIdx.x & 511;
    const int w = threadIdx.x;
    const long long base = (long long)b * 524288;
    const long long io = base + (long long)hr * 512 + w;
    const long long ig = base + (long long)(hr + 512) * 512 + w;

    const float mu = stats[b * 2 + 0], rstd = stats[b * 2 + 1];
    const float xo = X[io], xg = X[ig];
    const float p1w = pw1_w[0], p1b = pw1_b[0];

    const float yo = ((xo - mu) * rstd * ln1_g[hr * 512 + w] + ln1_b[hr * 512 + w]) * p1w + p1b;
    const float yg = ((xg - mu) * rstd * ln1_g[(hr + 512) * 512 + w] + ln1_b[(hr + 512) * 512 + w]) * p1w + p1b;

    __shared__ float gb[514];
    gb[w + 1] = yo * sigm(yg);
    if (w == 0) { gb[0] = 0.0f; gb[513] = 0.0f; }
    __syncthreads();

    const float z = gb[w] * dw1_w[0] + gb[w + 1] * dw1_w[1] + gb[w + 2] * dw1_w[2] + dw1_b[0];
    const float bnscale = rsqrtf(bn_v[0] + 1e-5f);

    const float u0 = z * dw2_w[0] + dw2_b[0];
    const float v0 = (u0 - bn_m[0]) * bnscale * bn_g[0] + bn_b[0];
    const float p0 = (v0 * sigm(v0)) * pw2_w[0] + pw2_b[0];

    const float u1 = z * dw2_w[1] + dw2_b[1];
    const float v1 = (u1 - bn_m[0]) * bnscale * bn_g[0] + bn_b[0];
    const float p1 = (v1 * sigm(v1)) * pw2_w[0] + pw2_b[0];

    X[io] = xo + p0;
    X[ig] = xg + p1;
}

// out = inputs + ((X - mu_b) * rstd_b * lnf_g + lnf_b). grid 65536, block 256.
__global__ void final_kernel(const float* __restrict__ inputs, const float* __restrict__ X,
                             const float* __restrict__ stats,
                             const float* __restrict__ lnf_g, const float* __restrict__ lnf_b,
                             float* __restrict__ out)
{
    const long long i = (long long)blockIdx.x * 256 + threadIdx.x;
    const int b = (int)(i >> 19);
    const int r = (int)(i & 524287);
    const float mu = stats[b * 2 + 0], rstd = stats[b * 2 + 1];
    out[i] = inputs[i] + ((X[i] - mu) * rstd * lnf_g[r] + lnf_b[r]);
}

extern "C" void kernel_launch(void* const* d_in, const int* in_sizes, int n_in,
                              void* d_out, int out_size, void* d_ws, size_t ws_size,
                              hipStream_t stream)
{
    (void)in_sizes; (void)n_in; (void)out_size; (void)ws_size;

    const float* inp   = (const float*)d_in[0];
    const float* l1_e1 = (const float*)d_in[1];
    const float* l1_d1 = (const float*)d_in[2];
    const float* l1_e2 = (const float*)d_in[3];
    const float* l1_d2 = (const float*)d_in[4];
    const float* wq    = (const float*)d_in[5];
    const float* bq    = (const float*)d_in[6];
    const float* wk    = (const float*)d_in[7];
    const float* bk    = (const float*)d_in[8];
    const float* wv    = (const float*)d_in[9];
    const float* bv    = (const float*)d_in[10];
    const float* wo    = (const float*)d_in[11];
    const float* bo    = (const float*)d_in[12];
    const float* ln1_g = (const float*)d_in[13];
    const float* ln1_b = (const float*)d_in[14];
    const float* pw1_w = (const float*)d_in[15];
    const float* pw1_b = (const float*)d_in[16];
    const float* dw1_w = (const float*)d_in[17];
    const float* dw1_b = (const float*)d_in[18];
    const float* dw2_w = (const float*)d_in[19];
    const float* dw2_b = (const float*)d_in[20];
    const float* bn_g  = (const float*)d_in[21];
    const float* bn_b  = (const float*)d_in[22];
    const float* bn_m  = (const float*)d_in[23];
    const float* bn_v  = (const float*)d_in[24];
    const float* pw2_w = (const float*)d_in[25];
    const float* pw2_b = (const float*)d_in[26];
    const float* l2_e1 = (const float*)d_in[27];
    const float* l2_d1 = (const float*)d_in[28];
    const float* l2_e2 = (const float*)d_in[29];
    const float* l2_d2 = (const float*)d_in[30];
    const float* lnf_g = (const float*)d_in[31];
    const float* lnf_b = (const float*)d_in[32];

    float* ws = (float*)d_ws;
    float* X  = ws;
    float* B1 = ws + 16777216LL;
    float* B2 = ws + 33554432LL;

    float* Q     = B1;
    float* Kt    = B1 + 8388608LL;
    float* V     = B2;
    float* W2    = B2 + 8388608LL;
    float* Bm    = B2 + 12582912LL;
    float* wpack = B2 + 13107200LL;
    float* stats = B2 + 13500416LL;

    const dim3 blk(256);
    auto gemm = [&](const float* A, const float* B, float* C, const float* res,
                    const float* bias, int M, int N, int K, float alpha, int sw,
                    long long bsA, long long bsB, long long bsC, int nb) {
        dim3 grid(N / 64, M / 64, nb);
        gemm_f32<<<grid, blk, 0, stream>>>(A, B, C, res, bias, N, K, alpha, sw, bsA, bsB, bsC);
    };

    // ---- LFFN1: X = inputs + 0.5 * lffn(inputs), 2 chunks of M=16384 ----
    for (int ch = 0; ch < 2; ++ch) {
        const float* Xc = inp + (long long)ch * 16384 * 512;
        float* Xo = X + (long long)ch * 16384 * 512;
        gemm(Xc, l1_e1, B1, nullptr, nullptr, 16384, 1024, 512, 1.0f, 0, 0, 0, 0, 1);
        gemm(B1, l1_d1, B2, nullptr, nullptr, 16384, 1024, 1024, 1.0f, 1, 0, 0, 0, 1); // swish
        gemm(B2, l1_e2, B1, nullptr, nullptr, 16384, 1024, 1024, 1.0f, 0, 0, 0, 0, 1);
        gemm(B1, l1_d2, Xo, Xc, nullptr, 16384, 512, 1024, 0.5f, 0, 0, 0, 0, 1);
    }

    // ---- MHLA: X += out_proj(linear-attention(X)) ----
    repack_qkv<<<1536, blk, 0, stream>>>(wq, wk, wv, wpack);
    gemm(X, wpack,            Q,  nullptr, bq, 32768, 256, 512, 1.0f, 0, 0, 0, 0, 1);
    gemm(X, wpack + 131072LL, Kt, nullptr, bk, 32768, 256, 512, 1.0f, 0, 0, 0, 0, 1);
    gemm(X, wpack + 262144LL, V,  nullptr, bv, 32768, 256, 512, 1.0f, 0, 0, 0, 0, 1);
    const float invd = 0.35355339059327373f;  // 1 / 64^0.25
    softmax_h<<<dim3(32, 2), dim3(1024), 0, stream>>>(Q, Kt, invd, invd);
    bm_kernel<<<128, blk, 0, stream>>>(Kt, V, Bm);
    w2_kernel<<<128, blk, 0, stream>>>(Bm, wo, W2);
    // X[b] += A[b] @ W2[b] + bo   (batched over b)
    gemm(Q, W2, X, X, bo, 1024, 512, 256, 1.0f, 0,
         1024LL * 256, 256LL * 512, 1024LL * 512, 32);

    // ---- Conv module: X += conv(X) ----
    stats_kernel<<<32, dim3(1024), 0, stream>>>(X, stats);
    conv_kernel<<<16384, dim3(512), 0, stream>>>(X, stats, ln1_g, ln1_b, pw1_w, pw1_b,
                                                 dw1_w, dw1_b, dw2_w, dw2_b,
                                                 bn_g, bn_b, bn_m, bn_v, pw2_w, pw2_b);

    // ---- LFFN2: X = X + 0.5 * lffn(X) ----
    for (int ch = 0; ch < 2; ++ch) {
        float* Xc = X + (long long)ch * 16384 * 512;
        gemm(Xc, l2_e1, B1, nullptr, nullptr, 16384, 1024, 512, 1.0f, 0, 0, 0, 0, 1);
        gemm(B1, l2_d1, B2, nullptr, nullptr, 16384, 1024, 1024, 1.0f, 1, 0, 0, 0, 1); // swish
        gemm(B2, l2_e2, B1, nullptr, nullptr, 16384, 1024, 1024, 1.0f, 0, 0, 0, 0, 1);
        gemm(B1, l2_d2, Xc, Xc, nullptr, 16384, 512, 1024, 0.5f, 0, 0, 0, 0, 1);
    }

    // ---- Final LN + residual to output ----
    stats_kernel<<<32, dim3(1024), 0, stream>>>(X, stats);
    final_kernel<<<65536, blk, 0, stream>>>(inp, X, stats, lnf_g, lnf_b, (float*)d_out);
}

// Round 2
// 1509.046 us; speedup vs baseline: 4.5098x; 4.5098x over previous
//
#include <hip/hip_runtime.h>
#include <cstdint>

typedef unsigned short u16;
typedef short bf16x8 __attribute__((ext_vector_type(8)));
typedef float f32x4 __attribute__((ext_vector_type(4)));
typedef u16 u16x8 __attribute__((ext_vector_type(8)));

static __device__ __forceinline__ float sigm(float x) { return 1.0f / (1.0f + expf(-x)); }
static __device__ __forceinline__ float b2f(u16 u) {
    union { unsigned i; float f; } v; v.i = ((unsigned)u) << 16; return v.f;
}
static __device__ __forceinline__ u16 f2b(float f) {
    unsigned x = __float_as_uint(f);
    x = x + 0x7fffu + ((x >> 16) & 1u);
    return (u16)(x >> 16);
}
static __device__ __forceinline__ void gload16(const u16* g, u16* l) {
    __builtin_amdgcn_global_load_lds((__attribute__((address_space(1))) void*)(void*)g,
                                     (__attribute__((address_space(3))) void*)l, 16, 0, 0);
}

// ---------------------------------------------------------------------------
// bf16 MFMA GEMM: C = [swish](alpha * A @ Bt^T [+bias(col)] [+res]).
// A [M][K] bf16 row-major, Bt [N][K] bf16 row-major (K-inner both).
// 128x128 tile, BK=64, 256 threads (4 waves, 2x2), double-buffered LDS,
// global_load_lds staging with pre-swizzled source (XOR slot^(row&7)).
// ---------------------------------------------------------------------------
__global__ __launch_bounds__(256) void gemm_bf16(
    const u16* A, const u16* Bt, float* outF, u16* outB,
    const float* res, const float* bias,
    int N, int K, float alpha, int do_swish,
    long long sA, long long sB, long long sC)
{
    __shared__ u16 lds[32768];  // 64 KB: buf0{A16K,B16K}, buf1{A16K,B16K}
    const int tid = threadIdx.x;
    const int lane = tid & 63;
    const int wr = ((tid >> 6) >> 1) * 64;
    const int wc = ((tid >> 6) & 1) * 64;
    const int m0 = blockIdx.y * 128;
    const int n0 = blockIdx.x * 128;
    const int bz = blockIdx.z;
    A += (long long)bz * sA;
    Bt += (long long)bz * sB;
    const long long cbase = (long long)bz * sC;

    const int srow = tid >> 3;   // 0..31
    const int sslot = tid & 7;   // 0..7

    f32x4 acc[4][4];
#pragma unroll
    for (int i = 0; i < 4; ++i)
#pragma unroll
        for (int j = 0; j < 4; ++j)
#pragma unroll
            for (int r = 0; r < 4; ++r) acc[i][j][r] = 0.0f;

    const u16* Abase = A + (long long)m0 * K;
    const u16* Bbase = Bt + (long long)n0 * K;
    const int NT = K >> 6;

    auto stage = [&](int buf, int kt) {
        const u16* Ab = Abase + kt * 64;
        const u16* Bb = Bbase + kt * 64;
        u16* LA = lds + buf * 16384;
        u16* LB = LA + 8192;
#pragma unroll
        for (int i = 0; i < 4; ++i) {
            const int row = srow + 32 * i;
            const int gs = (sslot ^ (row & 7)) * 8;
            gload16(Ab + (long long)row * K + gs, LA + row * 64 + sslot * 8);
            gload16(Bb + (long long)row * K + gs, LB + row * 64 + sslot * 8);
        }
    };

    auto compute = [&](int buf) {
        const u16* LA = lds + buf * 16384;
        const u16* LB = LA + 8192;
#pragma unroll
        for (int ks = 0; ks < 2; ++ks) {
            bf16x8 av[4], bv[4];
#pragma unroll
            for (int i = 0; i < 4; ++i) {
                const int ar = wr + i * 16 + (lane & 15);
                const int sl = ks * 4 + (lane >> 4);
                av[i] = *(const bf16x8*)(LA + ar * 64 + (sl ^ (ar & 7)) * 8);
                const int br = wc + i * 16 + (lane & 15);
                bv[i] = *(const bf16x8*)(LB + br * 64 + (sl ^ (br & 7)) * 8);
            }
#pragma unroll
            for (int i = 0; i < 4; ++i)
#pragma unroll
                for (int j = 0; j < 4; ++j)
                    acc[i][j] = __builtin_amdgcn_mfma_f32_16x16x32_bf16(av[i], bv[j], acc[i][j], 0, 0, 0);
        }
    };

    stage(0, 0);
    __syncthreads();
    int cur = 0;
    for (int kt = 0; kt < NT; ++kt) {
        if (kt + 1 < NT) stage(cur ^ 1, kt + 1);
        compute(cur);
        __syncthreads();
        cur ^= 1;
    }

    // epilogue: C row = (lane>>4)*4 + r, col = lane&15 (m89-verified layout)
#pragma unroll
    for (int j = 0; j < 4; ++j) {
        const int col = n0 + wc + j * 16 + (lane & 15);
        const float bs = bias ? bias[col] : 0.0f;
#pragma unroll
        for (int i = 0; i < 4; ++i) {
#pragma unroll
            for (int r = 0; r < 4; ++r) {
                const int row = m0 + wr + i * 16 + ((lane >> 4) << 2) + r;
                const long long idx = cbase + (long long)row * N + col;
                float v = alpha * acc[i][j][r] + bs;
                if (res) v += res[idx];
                if (do_swish) v = v * sigm(v);
                if (outF) outF[idx] = v;
                if (outB) outB[idx] = f2b(v);
            }
        }
    }
}

// fp32 w[K][N] -> bf16 wt[N][K] (tiled transpose). block (32,8), grid (N/32,K/32)
__global__ void wcvt_t(const float* __restrict__ w, u16* __restrict__ wt, int K, int N)
{
    __shared__ float t[32][33];
    const int n0 = blockIdx.x * 32, k0 = blockIdx.y * 32;
    for (int i = threadIdx.y; i < 32; i += 8)
        t[i][threadIdx.x] = w[(long long)(k0 + i) * N + n0 + threadIdx.x];
    __syncthreads();
    for (int i = threadIdx.y; i < 32; i += 8)
        wt[(long long)(n0 + i) * K + k0 + threadIdx.x] = f2b(t[threadIdx.x][i]);
}

// wq/wk/wv (4,512,64) fp32 -> qkvT[t][col=n*64+d][k=w] bf16. grid 1536, block 256.
__global__ void qkvpack_kernel(const float* __restrict__ wq, const float* __restrict__ wk,
                               const float* __restrict__ wv, u16* __restrict__ out)
{
    const int o = blockIdx.x * 256 + threadIdx.x;  // 0..393215
    const int t = o >> 17;
    const int r = o & 131071;
    const int col = r >> 9;
    const int k = r & 511;
    const float* src = (t == 0) ? wq : (t == 1) ? wk : wv;
    out[o] = f2b(src[(col >> 6) * 32768 + k * 64 + (col & 63)]);
}

// fp32 -> bf16, 8 elems/thread. grid 8192, block 256 (for 16,777,216 elems).
__global__ void cvt_bf16_kernel(const float* __restrict__ in, u16* __restrict__ out)
{
    const long long i = ((long long)blockIdx.x * 256 + threadIdx.x) * 8;
    const float4 a = *(const float4*)(in + i);
    const float4 b = *(const float4*)(in + i + 4);
    u16x8 o;
    o[0] = f2b(a.x); o[1] = f2b(a.y); o[2] = f2b(a.z); o[3] = f2b(a.w);
    o[4] = f2b(b.x); o[5] = f2b(b.y); o[6] = f2b(b.z); o[7] = f2b(b.w);
    *(u16x8*)(out + i) = o;
}

// In-place column softmax over H=1024 per batch on bf16 [32768][256].
// grid (32, 2) -> (batch, Q/K), block 1024: thread -> 2 cols x 128-row segment.
__global__ __launch_bounds__(1024) void softmax_bf16(u16* Qb, u16* Kb, float sc)
{
    u16* Xp = (blockIdx.y == 0) ? Qb : Kb;
    const int b = blockIdx.x;
    const int c2 = (threadIdx.x & 127) * 2;
    const int seg = threadIdx.x >> 7;
    const long long base = (long long)b * 262144;
    __shared__ float red[8][256];

    float m0 = -1e30f, m1 = -1e30f;
    for (int h = seg * 128; h < seg * 128 + 128; ++h) {
        const unsigned u = *(const unsigned*)(Xp + base + (long long)h * 256 + c2);
        m0 = fmaxf(m0, b2f((u16)(u & 0xffff)) * sc);
        m1 = fmaxf(m1, b2f((u16)(u >> 16)) * sc);
    }
    red[seg][c2] = m0; red[seg][c2 + 1] = m1;
    __syncthreads();
    m0 = -1e30f; m1 = -1e30f;
    for (int s = 0; s < 8; ++s) { m0 = fmaxf(m0, red[s][c2]); m1 = fmaxf(m1, red[s][c2 + 1]); }
    __syncthreads();

    float s0 = 0.0f, s1 = 0.0f;
    for (int h = seg * 128; h < seg * 128 + 128; ++h) {
        const unsigned u = *(const unsigned*)(Xp + base + (long long)h * 256 + c2);
        s0 += expf(b2f((u16)(u & 0xffff)) * sc - m0);
        s1 += expf(b2f((u16)(u >> 16)) * sc - m1);
    }
    red[seg][c2] = s0; red[seg][c2 + 1] = s1;
    __syncthreads();
    s0 = 0.0f; s1 = 0.0f;
    for (int s = 0; s < 8; ++s) { s0 += red[s][c2]; s1 += red[s][c2 + 1]; }
    const float i0 = 1.0f / s0, i1 = 1.0f / s1;

    for (int h = seg * 128; h < seg * 128 + 128; ++h) {
        u16* p = Xp + base + (long long)h * 256 + c2;
        const unsigned u = *(const unsigned*)p;
        const float e0 = expf(b2f((u16)(u & 0xffff)) * sc - m0) * i0;
        const float e1 = expf(b2f((u16)(u >> 16)) * sc - m1) * i1;
        *(unsigned*)p = (unsigned)f2b(e0) | ((unsigned)f2b(e1) << 16);
    }
}

// Bm[b,n,d,e] = sum_h Ksm[b,h,n,d] * V[b,h,n,e]  (bf16 in, fp32 out). grid 128.
__global__ __launch_bounds__(256) void bm_kernel(const u16* __restrict__ Ksm,
                                                 const u16* __restrict__ V,
                                                 float* __restrict__ Bm)
{
    const int b = blockIdx.x >> 2, n = blockIdx.x & 3;
    const long long base = (long long)b * 262144 + n * 64;
    __shared__ float Ks[64][64];
    __shared__ float Vs[64][64];
    const int tid = threadIdx.x;
    const int d = tid & 63, eg = tid >> 6;
    float acc[16] = {};

    for (int h0 = 0; h0 < 1024; h0 += 64) {
        const int cc = tid & 63, rg = tid >> 6;
        for (int r = 0; r < 16; ++r) {
            const int hh = rg * 16 + r;
            const long long gi = base + (long long)(h0 + hh) * 256 + cc;
            Ks[hh][cc] = b2f(Ksm[gi]);
            Vs[hh][cc] = b2f(V[gi]);
        }
        __syncthreads();
        for (int hh = 0; hh < 64; ++hh) {
            const float kd = Ks[hh][d];
#pragma unroll
            for (int j = 0; j < 16; ++j)
                acc[j] = fmaf(kd, Vs[hh][eg * 16 + j], acc[j]);
        }
        __syncthreads();
    }
    float* o = Bm + (long long)(b * 4 + n) * 4096 + d * 64 + eg * 16;
    for (int j = 0; j < 16; ++j) o[j] = acc[j];
}

// W2t[b][w][n*64+d] = sum_e Bm[b,n,d,e] * wo[n*64+e][w]  (bf16 out). grid 128.
__global__ __launch_bounds__(256) void w2t_kernel(const float* __restrict__ Bm,
                                                  const float* __restrict__ wo,
                                                  u16* __restrict__ W2t)
{
    const int b = blockIdx.x >> 2, n = blockIdx.x & 3;
    __shared__ float BmT[64][65];  // BmT[e][d]
    __shared__ float Ws[64][64];   // Ws[e][w_local]
    __shared__ float Ot[64][65];   // Ot[w_local][d]
    const int tid = threadIdx.x;
    const float* bm = Bm + (long long)(b * 4 + n) * 4096;

    {
        const int e2 = tid & 63, r0 = (tid >> 6) * 16;
        for (int r = 0; r < 16; ++r)
            BmT[e2][r0 + r] = bm[(long long)(r0 + r) * 64 + e2];
    }
    __syncthreads();

    const int d = tid & 63, wg = tid >> 6;
    for (int w0 = 0; w0 < 512; w0 += 64) {
        {
            const int ww = tid & 63, r0 = (tid >> 6) * 16;
            for (int r = 0; r < 16; ++r)
                Ws[r0 + r][ww] = wo[(long long)(n * 64 + r0 + r) * 512 + w0 + ww];
        }
        __syncthreads();
        float acc[16] = {};
        for (int e = 0; e < 64; ++e) {
            const float bv = BmT[e][d];
#pragma unroll
            for (int j = 0; j < 16; ++j)
                acc[j] = fmaf(bv, Ws[e][wg * 16 + j], acc[j]);
        }
#pragma unroll
        for (int j = 0; j < 16; ++j) Ot[wg * 16 + j][d] = acc[j];
        __syncthreads();
        const int wl = tid >> 2, ds = (tid & 3) * 16;
        u16 tmp[16];
#pragma unroll
        for (int j = 0; j < 16; ++j) tmp[j] = f2b(Ot[wl][ds + j]);
        u16* op = W2t + (long long)b * 131072 + (long long)(w0 + wl) * 256 + n * 64 + ds;
        *(u16x8*)op = *(const u16x8*)tmp;
        *(u16x8*)(op + 8) = *(const u16x8*)(tmp + 8);
        __syncthreads();
    }
}

// Per-batch mean / rstd over 524288 elements. grid 32, block 1024.
__global__ __launch_bounds__(1024) void stats_kernel(const float* __restrict__ X,
                                                     float* __restrict__ stats)
{
    const int b = blockIdx.x;
    const float* p = X + (long long)b * 524288;
    float s = 0.0f, ss = 0.0f;
    for (int i = threadIdx.x; i < 524288; i += 1024) {
        const float v = p[i];
        s += v; ss += v * v;
    }
    __shared__ float rs[1024];
    __shared__ float rss[1024];
    rs[threadIdx.x] = s; rss[threadIdx.x] = ss;
    __syncthreads();
    for (int off = 512; off > 0; off >>= 1) {
        if (threadIdx.x < (unsigned)off) {
            rs[threadIdx.x] += rs[threadIdx.x + off];
            rss[threadIdx.x] += rss[threadIdx.x + off];
        }
        __syncthreads();
    }
    if (threadIdx.x == 0) {
        const float mu = rs[0] / 524288.0f;
        const float var = rss[0] / 524288.0f - mu * mu;
        stats[b * 2 + 0] = mu;
        stats[b * 2 + 1] = rsqrtf(var + 1e-5f);
    }
}

// Fused conv module (LN->pw1->GLU->dw(1,3)->dw2+fold->BN->swish->pw2->+res).
// Writes X (fp32) and Xb (bf16). grid 32*512 (b,hr), block 512 (w).
__global__ __launch_bounds__(512) void conv_kernel(
    float* X, u16* __restrict__ Xb, const float* __restrict__ stats,
    const float* __restrict__ ln1_g, const float* __restrict__ ln1_b,
    const float* __restrict__ pw1_w, const float* __restrict__ pw1_b,
    const float* __restrict__ dw1_w, const float* __restrict__ dw1_b,
    const float* __restrict__ dw2_w, const float* __restrict__ dw2_b,
    const float* __restrict__ bn_g, const float* __restrict__ bn_b,
    const float* __restrict__ bn_m, const float* __restrict__ bn_v,
    const float* __restrict__ pw2_w, const float* __restrict__ pw2_b)
{
    const int b = blockIdx.x >> 9;
    const int hr = blockIdx.x & 511;
    const int w = threadIdx.x;
    const long long base = (long long)b * 524288;
    const long long io = base + (long long)hr * 512 + w;
    const long long ig = base + (long long)(hr + 512) * 512 + w;

    const float mu = stats[b * 2 + 0], rstd = stats[b * 2 + 1];
    const float xo = X[io], xg = X[ig];
    const float p1w = pw1_w[0], p1b = pw1_b[0];

    const float yo = ((xo - mu) * rstd * ln1_g[hr * 512 + w] + ln1_b[hr * 512 + w]) * p1w + p1b;
    const float yg = ((xg - mu) * rstd * ln1_g[(hr + 512) * 512 + w] + ln1_b[(hr + 512) * 512 + w]) * p1w + p1b;

    __shared__ float gb[514];
    gb[w + 1] = yo * sigm(yg);
    if (w == 0) { gb[0] = 0.0f; gb[513] = 0.0f; }
    __syncthreads();

    const float z = gb[w] * dw1_w[0] + gb[w + 1] * dw1_w[1] + gb[w + 2] * dw1_w[2] + dw1_b[0];
    const float bnscale = rsqrtf(bn_v[0] + 1e-5f);

    const float u0 = z * dw2_w[0] + dw2_b[0];
    const float v0 = (u0 - bn_m[0]) * bnscale * bn_g[0] + bn_b[0];
    const float p0 = (v0 * sigm(v0)) * pw2_w[0] + pw2_b[0];

    const float u1 = z * dw2_w[1] + dw2_b[1];
    const float v1 = (u1 - bn_m[0]) * bnscale * bn_g[0] + bn_b[0];
    const float p1 = (v1 * sigm(v1)) * pw2_w[0] + pw2_b[0];

    const float r0 = xo + p0, r1 = xg + p1;
    X[io] = r0; X[ig] = r1;
    Xb[io] = f2b(r0); Xb[ig] = f2b(r1);
}

// out = inputs + ((X - mu_b) * rstd_b * lnf_g + lnf_b). grid 65536, block 256.
__global__ void final_kernel(const float* __restrict__ inputs, const float* __restrict__ X,
                             const float* __restrict__ stats,
                             const float* __restrict__ lnf_g, const float* __restrict__ lnf_b,
                             float* __restrict__ out)
{
    const long long i = (long long)blockIdx.x * 256 + threadIdx.x;
    const int b = (int)(i >> 19);
    const int r = (int)(i & 524287);
    const float mu = stats[b * 2 + 0], rstd = stats[b * 2 + 1];
    out[i] = inputs[i] + ((X[i] - mu) * rstd * lnf_g[r] + lnf_b[r]);
}

extern "C" void kernel_launch(void* const* d_in, const int* in_sizes, int n_in,
                              void* d_out, int out_size, void* d_ws, size_t ws_size,
                              hipStream_t stream)
{
    (void)in_sizes; (void)n_in; (void)out_size; (void)ws_size;

    const float* inp   = (const float*)d_in[0];
    const float* l1_e1 = (const float*)d_in[1];
    const float* l1_d1 = (const float*)d_in[2];
    const float* l1_e2 = (const float*)d_in[3];
    const float* l1_d2 = (const float*)d_in[4];
    const float* wq    = (const float*)d_in[5];
    const float* bq    = (const float*)d_in[6];
    const float* wk    = (const float*)d_in[7];
    const float* bk    = (const float*)d_in[8];
    const float* wv    = (const float*)d_in[9];
    const float* bv    = (const float*)d_in[10];
    const float* wo    = (const float*)d_in[11];
    const float* bo    = (const float*)d_in[12];
    const float* ln1_g = (const float*)d_in[13];
    const float* ln1_b = (const float*)d_in[14];
    const float* pw1_w = (const float*)d_in[15];
    const float* pw1_b = (const float*)d_in[16];
    const float* dw1_w = (const float*)d_in[17];
    const float* dw1_b = (const float*)d_in[18];
    const float* dw2_w = (const float*)d_in[19];
    const float* dw2_b = (const float*)d_in[20];
    const float* bn_g  = (const float*)d_in[21];
    const float* bn_b  = (const float*)d_in[22];
    const float* bn_m  = (const float*)d_in[23];
    const float* bn_v  = (const float*)d_in[24];
    const float* pw2_w = (const float*)d_in[25];
    const float* pw2_b = (const float*)d_in[26];
    const float* l2_e1 = (const float*)d_in[27];
    const float* l2_d1 = (const float*)d_in[28];
    const float* l2_e2 = (const float*)d_in[29];
    const float* l2_d2 = (const float*)d_in[30];
    const float* lnf_g = (const float*)d_in[31];
    const float* lnf_b = (const float*)d_in[32];

    char* wsb = (char*)d_ws;
    float* X   = (float*)(wsb);                  // 67,108,864 B
    u16*   Xb  = (u16*)(wsb + 67108864);         // 33,554,432 B
    u16*   P1  = (u16*)(wsb + 100663296);        // 33,554,432 B
    u16*   P2  = (u16*)(wsb + 134217728);        // 33,554,432 B
    u16*   WT  = (u16*)(wsb + 167772160);        // 12,582,912 B
    u16*   qkvT = (u16*)(wsb + 180355072);       //    786,432 B
    float* stats = (float*)(wsb + 181141504);    //        256 B

    u16* l1_e1t = WT;
    u16* l1_d1t = WT + 524288;
    u16* l1_e2t = WT + 1572864;
    u16* l1_d2t = WT + 2621440;
    u16* l2_e1t = WT + 3145728;
    u16* l2_d1t = WT + 3670016;
    u16* l2_e2t = WT + 4718592;
    u16* l2_d2t = WT + 5767168;

    // MHLA overlays (P1/P2 dead between LFFNs)
    u16*   Qb  = P1;                             // [32768][256]
    u16*   Kb  = P1 + 8388608;
    u16*   Vb  = P2;
    u16*   W2t = P2 + 8388608;                   // [32][512][256]
    float* Bm  = (float*)(wsb + 134217728 + 25165824);  // [32][4][64][64]

    const dim3 tb(32, 8);
    wcvt_t<<<dim3(32, 16), tb, 0, stream>>>(l1_e1, l1_e1t, 512, 1024);
    wcvt_t<<<dim3(32, 32), tb, 0, stream>>>(l1_d1, l1_d1t, 1024, 1024);
    wcvt_t<<<dim3(32, 32), tb, 0, stream>>>(l1_e2, l1_e2t, 1024, 1024);
    wcvt_t<<<dim3(16, 32), tb, 0, stream>>>(l1_d2, l1_d2t, 1024, 512);
    wcvt_t<<<dim3(32, 16), tb, 0, stream>>>(l2_e1, l2_e1t, 512, 1024);
    wcvt_t<<<dim3(32, 32), tb, 0, stream>>>(l2_d1, l2_d1t, 1024, 1024);
    wcvt_t<<<dim3(32, 32), tb, 0, stream>>>(l2_e2, l2_e2t, 1024, 1024);
    wcvt_t<<<dim3(16, 32), tb, 0, stream>>>(l2_d2, l2_d2t, 1024, 512);
    qkvpack_kernel<<<1536, 256, 0, stream>>>(wq, wk, wv, qkvT);
    cvt_bf16_kernel<<<8192, 256, 0, stream>>>(inp, Xb);

    auto G = [&](const u16* A, const u16* Bt, float* oF, u16* oB,
                 const float* res, const float* bias, int M, int N, int K,
                 float alpha, int sw, long long sA, long long sB, long long sC, int nb) {
        dim3 grid(N / 128, M / 128, nb);
        gemm_bf16<<<grid, 256, 0, stream>>>(A, Bt, oF, oB, res, bias, N, K, alpha, sw, sA, sB, sC);
    };

    // ---- LFFN1: X = inputs + 0.5*lffn(inputs); also writes Xb ----
    for (int ch = 0; ch < 2; ++ch) {
        const long long off = (long long)ch * 16384 * 512;
        G(Xb + off, l1_e1t, nullptr, P1, nullptr, nullptr, 16384, 1024, 512, 1.0f, 0, 0, 0, 0, 1);
        G(P1, l1_d1t, nullptr, P2, nullptr, nullptr, 16384, 1024, 1024, 1.0f, 1, 0, 0, 0, 1);
        G(P2, l1_e2t, nullptr, P1, nullptr, nullptr, 16384, 1024, 1024, 1.0f, 0, 0, 0, 0, 1);
        G(P1, l1_d2t, X + off, Xb + off, inp + off, nullptr, 16384, 512, 1024, 0.5f, 0, 0, 0, 0, 1);
    }

    // ---- MHLA: X += A @ (Bm @ wo) + bo ----
    G(Xb, qkvT,          nullptr, Qb, nullptr, bq, 32768, 256, 512, 1.0f, 0, 0, 0, 0, 1);
    G(Xb, qkvT + 131072, nullptr, Kb, nullptr, bk, 32768, 256, 512, 1.0f, 0, 0, 0, 0, 1);
    G(Xb, qkvT + 262144, nullptr, Vb, nullptr, bv, 32768, 256, 512, 1.0f, 0, 0, 0, 0, 1);
    softmax_bf16<<<dim3(32, 2), 1024, 0, stream>>>(Qb, Kb, 0.35355339059327373f);
    bm_kernel<<<128, 256, 0, stream>>>(Kb, Vb, Bm);
    w2t_kernel<<<128, 256, 0, stream>>>(Bm, wo, W2t);
    G(Qb, W2t, X, nullptr, X, bo, 1024, 512, 256, 1.0f, 0,
      262144LL, 131072LL, 524288LL, 32);

    // ---- Conv module: X += conv(X); writes Xb ----
    stats_kernel<<<32, 1024, 0, stream>>>(X, stats);
    conv_kernel<<<16384, 512, 0, stream>>>(X, Xb, stats, ln1_g, ln1_b, pw1_w, pw1_b,
                                           dw1_w, dw1_b, dw2_w, dw2_b,
                                           bn_g, bn_b, bn_m, bn_v, pw2_w, pw2_b);

    // ---- LFFN2: X = X + 0.5*lffn(X) ----
    for (int ch = 0; ch < 2; ++ch) {
        const long long off = (long long)ch * 16384 * 512;
        G(Xb + off, l2_e1t, nullptr, P1, nullptr, nullptr, 16384, 1024, 512, 1.0f, 0, 0, 0, 0, 1);
        G(P1, l2_d1t, nullptr, P2, nullptr, nullptr, 16384, 1024, 1024, 1.0f, 1, 0, 0, 0, 1);
        G(P2, l2_e2t, nullptr, P1, nullptr, nullptr, 16384, 1024, 1024, 1.0f, 0, 0, 0, 0, 1);
        G(P1, l2_d2t, X + off, nullptr, X + off, nullptr, 16384, 512, 1024, 0.5f, 0, 0, 0, 0, 1);
    }

    // ---- Final LN + residual ----
    stats_kernel<<<32, 1024, 0, stream>>>(X, stats);
    final_kernel<<<65536, 256, 0, stream>>>(inp, X, stats, lnf_g, lnf_b, (float*)d_out);
}

// Round 3
// 794.165 us; speedup vs baseline: 8.5694x; 1.9002x over previous
//
#include <hip/hip_runtime.h>
#include <cstdint>

typedef unsigned short u16;
typedef short bf16x8 __attribute__((ext_vector_type(8)));
typedef float f32x4 __attribute__((ext_vector_type(4)));
typedef u16 u16x8 __attribute__((ext_vector_type(8)));

static __device__ __forceinline__ float sigm(float x) { return 1.0f / (1.0f + expf(-x)); }
static __device__ __forceinline__ float b2f(u16 u) {
    union { unsigned i; float f; } v; v.i = ((unsigned)u) << 16; return v.f;
}
static __device__ __forceinline__ u16 f2b(float f) {
    unsigned x = __float_as_uint(f);
    x = x + 0x7fffu + ((x >> 16) & 1u);
    return (u16)(x >> 16);
}
static __device__ __forceinline__ void gload16(const u16* g, u16* l) {
    __builtin_amdgcn_global_load_lds((__attribute__((address_space(1))) void*)(void*)g,
                                     (__attribute__((address_space(3))) void*)l, 16, 0, 0);
}

// ---------------------------------------------------------------------------
// bf16 MFMA GEMM: C = [swish](alpha * A @ Bt^T [+bias(col)] [+res]).
// A [M][lda] bf16 row-major, Bt [N][K] bf16 row-major (K-inner both).
// 128x128 tile, BK=64, 4 waves, double-buffered LDS, global_load_lds staging
// with pre-swizzled source (XOR slot^(row&7)).  Optional per-block (sum,sumsq)
// partial written to partials[flat_block] for fused LayerNorm stats.
// ---------------------------------------------------------------------------
__global__ __launch_bounds__(256) void gemm_bf16(
    const u16* A, const u16* Bt, float* outF, u16* outB,
    const float* res, const float* bias, float2* partials,
    int N, int K, int lda, float alpha, int do_swish,
    long long sA, long long sB, long long sC)
{
    __shared__ u16 lds[32768];  // 64 KB: 2 bufs x {A 16K, B 16K}
    const int tid = threadIdx.x;
    const int lane = tid & 63;
    const int wr = ((tid >> 6) >> 1) * 64;
    const int wc = ((tid >> 6) & 1) * 64;
    const int m0 = blockIdx.y * 128;
    const int n0 = blockIdx.x * 128;
    const int bz = blockIdx.z;
    const long long cbase = (long long)bz * sC;

    const int srow = tid >> 3;   // 0..31
    const int sslot = tid & 7;   // 0..7

    f32x4 acc[4][4];
#pragma unroll
    for (int i = 0; i < 4; ++i)
#pragma unroll
        for (int j = 0; j < 4; ++j)
#pragma unroll
            for (int r = 0; r < 4; ++r) acc[i][j][r] = 0.0f;

    const u16* Abase = A + (long long)bz * sA + (long long)m0 * lda;
    const u16* Bbase = Bt + (long long)bz * sB + (long long)n0 * K;
    const int NT = K >> 6;

    auto stage = [&](int buf, int kt) {
        const u16* Ab = Abase + kt * 64;
        const u16* Bb = Bbase + kt * 64;
        u16* LA = lds + buf * 16384;
        u16* LB = LA + 8192;
#pragma unroll
        for (int i = 0; i < 4; ++i) {
            const int row = srow + 32 * i;
            const int gs = (sslot ^ (row & 7)) * 8;
            gload16(Ab + (long long)row * lda + gs, LA + row * 64 + sslot * 8);
            gload16(Bb + (long long)row * K + gs, LB + row * 64 + sslot * 8);
        }
    };

    auto compute = [&](int buf) {
        const u16* LA = lds + buf * 16384;
        const u16* LB = LA + 8192;
#pragma unroll
        for (int ks = 0; ks < 2; ++ks) {
            bf16x8 av[4], bv[4];
#pragma unroll
            for (int i = 0; i < 4; ++i) {
                const int ar = wr + i * 16 + (lane & 15);
                const int sl = ks * 4 + (lane >> 4);
                av[i] = *(const bf16x8*)(LA + ar * 64 + (sl ^ (ar & 7)) * 8);
                const int br = wc + i * 16 + (lane & 15);
                bv[i] = *(const bf16x8*)(LB + br * 64 + (sl ^ (br & 7)) * 8);
            }
#pragma unroll
            for (int i = 0; i < 4; ++i)
#pragma unroll
                for (int j = 0; j < 4; ++j)
                    acc[i][j] = __builtin_amdgcn_mfma_f32_16x16x32_bf16(av[i], bv[j], acc[i][j], 0, 0, 0);
        }
    };

    stage(0, 0);
    __syncthreads();
    int cur = 0;
    for (int kt = 0; kt < NT; ++kt) {
        if (kt + 1 < NT) stage(cur ^ 1, kt + 1);
        compute(cur);
        __syncthreads();
        cur ^= 1;
    }

    float sacc = 0.0f, ssacc = 0.0f;
    // epilogue: C row = (lane>>4)*4 + r, col = lane&15 (m89-verified layout)
#pragma unroll
    for (int j = 0; j < 4; ++j) {
        const int col = n0 + wc + j * 16 + (lane & 15);
        const float bs = bias ? bias[col] : 0.0f;
#pragma unroll
        for (int i = 0; i < 4; ++i) {
#pragma unroll
            for (int r = 0; r < 4; ++r) {
                const int row = m0 + wr + i * 16 + ((lane >> 4) << 2) + r;
                const long long idx = cbase + (long long)row * N + col;
                float v = alpha * acc[i][j][r] + bs;
                if (res) v += res[idx];
                if (do_swish) v = v * sigm(v);
                sacc += v; ssacc = fmaf(v, v, ssacc);
                if (outF) outF[idx] = v;
                if (outB) outB[idx] = f2b(v);
            }
        }
    }

    if (partials) {
#pragma unroll
        for (int off = 32; off; off >>= 1) {
            sacc += __shfl_down(sacc, off);
            ssacc += __shfl_down(ssacc, off);
        }
        float* rs = (float*)lds;
        if ((tid & 63) == 0) { rs[tid >> 6] = sacc; rs[4 + (tid >> 6)] = ssacc; }
        __syncthreads();
        if (tid == 0) {
            const float S = rs[0] + rs[1] + rs[2] + rs[3];
            const float SS = rs[4] + rs[5] + rs[6] + rs[7];
            const int flat = (int)((blockIdx.z * gridDim.y + blockIdx.y) * gridDim.x + blockIdx.x);
            partials[flat] = make_float2(S, SS);
        }
    }
}

// 1024 partials (32 per batch, batch-ordered) -> stats[b*2]={mu,rstd}. 1 block.
__global__ __launch_bounds__(1024) void stats_reduce(const float2* __restrict__ p,
                                                     float* __restrict__ st)
{
    const int tid = threadIdx.x;
    float2 v = p[tid];
    float s = v.x, ss = v.y;
#pragma unroll
    for (int off = 16; off; off >>= 1) {
        s += __shfl_down(s, off, 32);
        ss += __shfl_down(ss, off, 32);
    }
    if ((tid & 31) == 0) {
        const int b = tid >> 5;
        const float mu = s / 524288.0f;
        const float var = ss / 524288.0f - mu * mu;
        st[b * 2 + 0] = mu;
        st[b * 2 + 1] = rsqrtf(var + 1e-5f);
    }
}

// fp32 w[K][N] -> bf16 wt[N][K] (tiled transpose). block (32,8), grid (N/32,K/32)
__global__ void wcvt_t(const float* __restrict__ w, u16* __restrict__ wt, int K, int N)
{
    __shared__ float t[32][33];
    const int n0 = blockIdx.x * 32, k0 = blockIdx.y * 32;
    for (int i = threadIdx.y; i < 32; i += 8)
        t[i][threadIdx.x] = w[(long long)(k0 + i) * N + n0 + threadIdx.x];
    __syncthreads();
    for (int i = threadIdx.y; i < 32; i += 8)
        wt[(long long)(n0 + i) * K + k0 + threadIdx.x] = f2b(t[threadIdx.x][i]);
}

// wq/wk/wv (4,512,64) fp32 -> qkvT[row=t*256+n*64+d][k=w] bf16 [768][512].
__global__ void qkvpack_kernel(const float* __restrict__ wq, const float* __restrict__ wk,
                               const float* __restrict__ wv, u16* __restrict__ out)
{
    const int o = blockIdx.x * 256 + threadIdx.x;  // 0..393215
    const int t = o >> 17;
    const int r = o & 131071;
    const int col = r >> 9;
    const int k = r & 511;
    const float* src = (t == 0) ? wq : (t == 1) ? wk : wv;
    out[o] = f2b(src[(col >> 6) * 32768 + k * 64 + (col & 63)]);
}

__global__ void biaspack_kernel(const float* __restrict__ bq, const float* __restrict__ bk,
                                const float* __restrict__ bv, float* __restrict__ out)
{
    const int i = blockIdx.x * 256 + threadIdx.x;  // 0..767
    const float* s = (i < 256) ? bq : (i < 512) ? bk : bv;
    out[i] = s[i & 255];
}

// fp32 -> bf16, 8 elems/thread.
__global__ void cvt_bf16_kernel(const float* __restrict__ in, u16* __restrict__ out)
{
    const long long i = ((long long)blockIdx.x * 256 + threadIdx.x) * 8;
    const float4 a = *(const float4*)(in + i);
    const float4 b = *(const float4*)(in + i + 4);
    u16x8 o;
    o[0] = f2b(a.x); o[1] = f2b(a.y); o[2] = f2b(a.z); o[3] = f2b(a.w);
    o[4] = f2b(b.x); o[5] = f2b(b.y); o[6] = f2b(b.z); o[7] = f2b(b.w);
    *(u16x8*)(out + i) = o;
}

// Column softmax over H=1024 on QKV [32768][768] bf16, in place, pre-scale sc.
// grid (32, 8): (batch, 64-col group over Q[0..255]+K[256..511]); block 256:
// thread -> col-pair (tid&31)*2, segment tid>>5 (128 rows). Online max+sum.
__global__ __launch_bounds__(256) void softmax_qkv(u16* __restrict__ QKV, float sc)
{
    const int b = blockIdx.x;
    const int cbase = blockIdx.y * 64;
    const int pr = (threadIdx.x & 31) * 2;
    const int seg = threadIdx.x >> 5;
    u16* base = QKV + (long long)b * 786432 + cbase + pr;

    __shared__ float red_m[8][64];
    __shared__ float red_s[8][64];

    float m0 = -1e30f, m1 = -1e30f, s0 = 0.0f, s1 = 0.0f;
    for (int h = seg * 128; h < seg * 128 + 128; ++h) {
        const unsigned u = *(const unsigned*)(base + (long long)h * 768);
        const float v0 = b2f((u16)(u & 0xffff)) * sc;
        const float v1 = b2f((u16)(u >> 16)) * sc;
        const float nm0 = fmaxf(m0, v0), nm1 = fmaxf(m1, v1);
        s0 = s0 * __expf(m0 - nm0) + __expf(v0 - nm0);
        s1 = s1 * __expf(m1 - nm1) + __expf(v1 - nm1);
        m0 = nm0; m1 = nm1;
    }
    red_m[seg][pr] = m0; red_m[seg][pr + 1] = m1;
    red_s[seg][pr] = s0; red_s[seg][pr + 1] = s1;
    __syncthreads();

    float M0 = -1e30f, M1 = -1e30f;
#pragma unroll
    for (int s = 0; s < 8; ++s) { M0 = fmaxf(M0, red_m[s][pr]); M1 = fmaxf(M1, red_m[s][pr + 1]); }
    float S0 = 0.0f, S1 = 0.0f;
#pragma unroll
    for (int s = 0; s < 8; ++s) {
        S0 += red_s[s][pr] * __expf(red_m[s][pr] - M0);
        S1 += red_s[s][pr + 1] * __expf(red_m[s][pr + 1] - M1);
    }
    const float i0 = 1.0f / S0, i1 = 1.0f / S1;

    for (int h = seg * 128; h < seg * 128 + 128; ++h) {
        u16* p = base + (long long)h * 768;
        const unsigned u = *(const unsigned*)p;
        const float e0 = __expf(b2f((u16)(u & 0xffff)) * sc - M0) * i0;
        const float e1 = __expf(b2f((u16)(u >> 16)) * sc - M1) * i1;
        *(unsigned*)p = (unsigned)f2b(e0) | ((unsigned)f2b(e1) << 16);
    }
}

// Bm[b,n,d,e] = sum_h Ksm[b,h,n,d] * V[b,h,n,e] from QKV [32768][768]. grid 128.
__global__ __launch_bounds__(256) void bm_kernel(const u16* __restrict__ QKV,
                                                 float* __restrict__ Bm)
{
    const int b = blockIdx.x >> 2, n = blockIdx.x & 3;
    const long long kbase = (long long)b * 786432 + 256 + n * 64;
    const long long vbase = (long long)b * 786432 + 512 + n * 64;
    __shared__ float Ks[64][64];
    __shared__ float Vs[64][64];
    const int tid = threadIdx.x;
    const int d = tid & 63, eg = tid >> 6;
    float acc[16] = {};

    for (int h0 = 0; h0 < 1024; h0 += 64) {
        const int cc = tid & 63, rg = tid >> 6;
        for (int r = 0; r < 16; ++r) {
            const int hh = rg * 16 + r;
            Ks[hh][cc] = b2f(QKV[kbase + (long long)(h0 + hh) * 768 + cc]);
            Vs[hh][cc] = b2f(QKV[vbase + (long long)(h0 + hh) * 768 + cc]);
        }
        __syncthreads();
        for (int hh = 0; hh < 64; ++hh) {
            const float kd = Ks[hh][d];
#pragma unroll
            for (int j = 0; j < 16; ++j)
                acc[j] = fmaf(kd, Vs[hh][eg * 16 + j], acc[j]);
        }
        __syncthreads();
    }
    float* o = Bm + (long long)(b * 4 + n) * 4096 + d * 64 + eg * 16;
    for (int j = 0; j < 16; ++j) o[j] = acc[j];
}

// W2t_att[b][w][n*64+d] = sum_e Bm[b,n,d,e] * wo[n*64+e][w] (bf16 out). grid 128.
__global__ __launch_bounds__(256) void w2t_kernel(const float* __restrict__ Bm,
                                                  const float* __restrict__ wo,
                                                  u16* __restrict__ W2t)
{
    const int b = blockIdx.x >> 2, n = blockIdx.x & 3;
    __shared__ float BmT[64][65];
    __shared__ float Ws[64][64];
    __shared__ float Ot[64][65];
    const int tid = threadIdx.x;
    const float* bm = Bm + (long long)(b * 4 + n) * 4096;

    {
        const int e2 = tid & 63, r0 = (tid >> 6) * 16;
        for (int r = 0; r < 16; ++r)
            BmT[e2][r0 + r] = bm[(long long)(r0 + r) * 64 + e2];
    }
    __syncthreads();

    const int d = tid & 63, wg = tid >> 6;
    for (int w0 = 0; w0 < 512; w0 += 64) {
        {
            const int ww = tid & 63, r0 = (tid >> 6) * 16;
            for (int r = 0; r < 16; ++r)
                Ws[r0 + r][ww] = wo[(long long)(n * 64 + r0 + r) * 512 + w0 + ww];
        }
        __syncthreads();
        float acc[16] = {};
        for (int e = 0; e < 64; ++e) {
            const float bv = BmT[e][d];
#pragma unroll
            for (int j = 0; j < 16; ++j)
                acc[j] = fmaf(bv, Ws[e][wg * 16 + j], acc[j]);
        }
#pragma unroll
        for (int j = 0; j < 16; ++j) Ot[wg * 16 + j][d] = acc[j];
        __syncthreads();
        const int wl = tid >> 2, ds = (tid & 3) * 16;
        u16 tmp[16];
#pragma unroll
        for (int j = 0; j < 16; ++j) tmp[j] = f2b(Ot[wl][ds + j]);
        u16* op = W2t + (long long)b * 131072 + (long long)(w0 + wl) * 256 + n * 64 + ds;
        *(u16x8*)op = *(const u16x8*)tmp;
        *(u16x8*)(op + 8) = *(const u16x8*)(tmp + 8);
        __syncthreads();
    }
}

// Fused conv module (LN->pw1->GLU->dw(1,3)->dw2+fold->BN->swish->pw2->+res).
// Writes X (fp32) and Xb (bf16). grid 32*512 (b,hr), block 512 (w).
__global__ __launch_bounds__(512) void conv_kernel(
    float* X, u16* __restrict__ Xb, const float* __restrict__ st,
    const float* __restrict__ ln1_g, const float* __restrict__ ln1_b,
    const float* __restrict__ pw1_w, const float* __restrict__ pw1_b,
    const float* __restrict__ dw1_w, const float* __restrict__ dw1_b,
    const float* __restrict__ dw2_w, const float* __restrict__ dw2_b,
    const float* __restrict__ bn_g, const float* __restrict__ bn_b,
    const float* __restrict__ bn_m, const float* __restrict__ bn_v,
    const float* __restrict__ pw2_w, const float* __restrict__ pw2_b)
{
    const int b = blockIdx.x >> 9;
    const int hr = blockIdx.x & 511;
    const int w = threadIdx.x;
    const long long base = (long long)b * 524288;
    const long long io = base + (long long)hr * 512 + w;
    const long long ig = base + (long long)(hr + 512) * 512 + w;

    const float mu = st[b * 2 + 0], rstd = st[b * 2 + 1];
    const float xo = X[io], xg = X[ig];
    const float p1w = pw1_w[0], p1b = pw1_b[0];

    const float yo = ((xo - mu) * rstd * ln1_g[hr * 512 + w] + ln1_b[hr * 512 + w]) * p1w + p1b;
    const float yg = ((xg - mu) * rstd * ln1_g[(hr + 512) * 512 + w] + ln1_b[(hr + 512) * 512 + w]) * p1w + p1b;

    __shared__ float gb[514];
    gb[w + 1] = yo * sigm(yg);
    if (w == 0) { gb[0] = 0.0f; gb[513] = 0.0f; }
    __syncthreads();

    const float z = gb[w] * dw1_w[0] + gb[w + 1] * dw1_w[1] + gb[w + 2] * dw1_w[2] + dw1_b[0];
    const float bnscale = rsqrtf(bn_v[0] + 1e-5f);

    const float u0 = z * dw2_w[0] + dw2_b[0];
    const float v0 = (u0 - bn_m[0]) * bnscale * bn_g[0] + bn_b[0];
    const float p0 = (v0 * sigm(v0)) * pw2_w[0] + pw2_b[0];

    const float u1 = z * dw2_w[1] + dw2_b[1];
    const float v1 = (u1 - bn_m[0]) * bnscale * bn_g[0] + bn_b[0];
    const float p1 = (v1 * sigm(v1)) * pw2_w[0] + pw2_b[0];

    const float r0 = xo + p0, r1 = xg + p1;
    X[io] = r0; X[ig] = r1;
    Xb[io] = f2b(r0); Xb[ig] = f2b(r1);
}

// out = inputs + ((X - mu_b) * rstd_b * lnf_g + lnf_b). float4. grid 16384x256.
__global__ void final_kernel(const float* __restrict__ inputs, const float* __restrict__ X,
                             const float* __restrict__ st,
                             const float* __restrict__ lnf_g, const float* __restrict__ lnf_b,
                             float* __restrict__ out)
{
    const long long i = ((long long)blockIdx.x * 256 + threadIdx.x) * 4;
    const int b = (int)(i >> 19);
    const int r = (int)(i & 524287);
    const float mu = st[b * 2 + 0], rstd = st[b * 2 + 1];
    const float4 x = *(const float4*)(X + i);
    const float4 in4 = *(const float4*)(inputs + i);
    const float4 g = *(const float4*)(lnf_g + r);
    const float4 bb = *(const float4*)(lnf_b + r);
    float4 o;
    o.x = in4.x + (x.x - mu) * rstd * g.x + bb.x;
    o.y = in4.y + (x.y - mu) * rstd * g.y + bb.y;
    o.z = in4.z + (x.z - mu) * rstd * g.z + bb.z;
    o.w = in4.w + (x.w - mu) * rstd * g.w + bb.w;
    *(float4*)(out + i) = o;
}

extern "C" void kernel_launch(void* const* d_in, const int* in_sizes, int n_in,
                              void* d_out, int out_size, void* d_ws, size_t ws_size,
                              hipStream_t stream)
{
    (void)in_sizes; (void)n_in; (void)out_size; (void)ws_size;

    const float* inp   = (const float*)d_in[0];
    const float* l1_e1 = (const float*)d_in[1];
    const float* l1_d1 = (const float*)d_in[2];
    const float* l1_e2 = (const float*)d_in[3];
    const float* l1_d2 = (const float*)d_in[4];
    const float* wq    = (const float*)d_in[5];
    const float* bq    = (const float*)d_in[6];
    const float* wk    = (const float*)d_in[7];
    const float* bk    = (const float*)d_in[8];
    const float* wv    = (const float*)d_in[9];
    const float* bv    = (const float*)d_in[10];
    const float* wo    = (const float*)d_in[11];
    const float* bo    = (const float*)d_in[12];
    const float* ln1_g = (const float*)d_in[13];
    const float* ln1_b = (const float*)d_in[14];
    const float* pw1_w = (const float*)d_in[15];
    const float* pw1_b = (const float*)d_in[16];
    const float* dw1_w = (const float*)d_in[17];
    const float* dw1_b = (const float*)d_in[18];
    const float* dw2_w = (const float*)d_in[19];
    const float* dw2_b = (const float*)d_in[20];
    const float* bn_g  = (const float*)d_in[21];
    const float* bn_b  = (const float*)d_in[22];
    const float* bn_m  = (const float*)d_in[23];
    const float* bn_v  = (const float*)d_in[24];
    const float* pw2_w = (const float*)d_in[25];
    const float* pw2_b = (const float*)d_in[26];
    const float* l2_e1 = (const float*)d_in[27];
    const float* l2_d1 = (const float*)d_in[28];
    const float* l2_e2 = (const float*)d_in[29];
    const float* l2_d2 = (const float*)d_in[30];
    const float* lnf_g = (const float*)d_in[31];
    const float* lnf_b = (const float*)d_in[32];

    char* wsb = (char*)d_ws;
    float* X  = (float*)(wsb);                         // 67,108,864 B
    u16*   Xb = (u16*)(wsb + 67108864);                // 33,554,432 B
    char*  U  = wsb + 100663296;                       // 67,108,864 B union region

    // precompute-phase overlays in U
    u16* l1_d1t = (u16*)(U + 0);
    u16* l1_e1b = (u16*)(U + 2097152);
    u16* l1_d2t = (u16*)(U + 3145728);
    u16* l1_e2b = (u16*)(U + 4194304);
    u16* l2_d1t = (u16*)(U + 6291456);
    u16* l2_e1b = (u16*)(U + 8388608);
    u16* l2_d2t = (u16*)(U + 9437184);
    u16* l2_e2b = (u16*)(U + 10485760);
    // LFFN-phase overlay
    u16* H = (u16*)U;                                  // [32768][1024] bf16
    // MHLA-phase overlays
    u16*   QKV    = (u16*)U;                           // [32768][768] bf16
    u16*   W2t_at = (u16*)(U + 50331648);              // [32][512][256] bf16
    float* Bm     = (float*)(U + 58720256);            // [32][4][64][64] fp32

    // persistent region
    char* P = wsb + 167772160;
    u16*    W1t_l1  = (u16*)(P + 0);
    u16*    W2t_l1  = (u16*)(P + 1048576);
    u16*    W1t_l2  = (u16*)(P + 2097152);
    u16*    W2t_l2  = (u16*)(P + 3145728);
    u16*    qkvT    = (u16*)(P + 4194304);             // [768][512]
    float*  qkvBias = (float*)(P + 4980736);           // 768
    float2* part0   = (float2*)(P + 4983808);          // 1024 float2
    float2* part1   = (float2*)(P + 4992000);
    float*  st0     = (float*)(P + 5000192);           // 64
    float*  st1     = (float*)(P + 5000448);

    auto G = [&](const u16* A, const u16* Bt, float* oF, u16* oB,
                 const float* res, const float* bias, float2* parts,
                 int M, int N, int K, int lda, float alpha, int sw,
                 long long sA, long long sB, long long sC, int nb) {
        dim3 grid(N / 128, M / 128, nb);
        gemm_bf16<<<grid, 256, 0, stream>>>(A, Bt, oF, oB, res, bias, parts,
                                            N, K, lda, alpha, sw, sA, sB, sC);
    };
    const dim3 tb(32, 8);

    // ---- weight prep (bf16 conversions + packed layouts) ----
    cvt_bf16_kernel<<<8192, 256, 0, stream>>>(inp, Xb);
    wcvt_t<<<dim3(32, 32), tb, 0, stream>>>(l1_d1, l1_d1t, 1024, 1024);
    cvt_bf16_kernel<<<256, 256, 0, stream>>>(l1_e1, l1_e1b);
    wcvt_t<<<dim3(16, 32), tb, 0, stream>>>(l1_d2, l1_d2t, 1024, 512);
    cvt_bf16_kernel<<<512, 256, 0, stream>>>(l1_e2, l1_e2b);
    wcvt_t<<<dim3(32, 32), tb, 0, stream>>>(l2_d1, l2_d1t, 1024, 1024);
    cvt_bf16_kernel<<<256, 256, 0, stream>>>(l2_e1, l2_e1b);
    wcvt_t<<<dim3(16, 32), tb, 0, stream>>>(l2_d2, l2_d2t, 1024, 512);
    cvt_bf16_kernel<<<512, 256, 0, stream>>>(l2_e2, l2_e2b);
    qkvpack_kernel<<<1536, 256, 0, stream>>>(wq, wk, wv, qkvT);
    biaspack_kernel<<<3, 256, 0, stream>>>(bq, bk, bv, qkvBias);

    // ---- fold LFFN weight pairs: W1t[n,k] = (e1@d1)^T, W2t[n,k] = (e2@d2)^T ----
    G(l1_d1t, l1_e1b, nullptr, W1t_l1, nullptr, nullptr, nullptr, 1024, 512, 1024, 1024, 1.0f, 0, 0, 0, 0, 1);
    G(l1_d2t, l1_e2b, nullptr, W2t_l1, nullptr, nullptr, nullptr, 512, 1024, 1024, 1024, 1.0f, 0, 0, 0, 0, 1);
    G(l2_d1t, l2_e1b, nullptr, W1t_l2, nullptr, nullptr, nullptr, 1024, 512, 1024, 1024, 1.0f, 0, 0, 0, 0, 1);
    G(l2_d2t, l2_e2b, nullptr, W2t_l2, nullptr, nullptr, nullptr, 512, 1024, 1024, 1024, 1.0f, 0, 0, 0, 0, 1);

    // ---- LFFN1: X = inputs + 0.5 * (swish(x@W1) @ W2) ----
    G(Xb, W1t_l1, nullptr, H, nullptr, nullptr, nullptr, 32768, 1024, 512, 512, 1.0f, 1, 0, 0, 0, 1);
    G(H, W2t_l1, X, Xb, inp, nullptr, nullptr, 32768, 512, 1024, 1024, 0.5f, 0, 0, 0, 0, 1);

    // ---- MHLA: X += Q_sm @ (Bm @ wo) + bo ----
    G(Xb, qkvT, nullptr, QKV, nullptr, qkvBias, nullptr, 32768, 768, 512, 512, 1.0f, 0, 0, 0, 0, 1);
    softmax_qkv<<<dim3(32, 8), 256, 0, stream>>>(QKV, 0.35355339059327373f);
    bm_kernel<<<128, 256, 0, stream>>>(QKV, Bm);
    w2t_kernel<<<128, 256, 0, stream>>>(Bm, wo, W2t_at);
    G(QKV, W2t_at, X, nullptr, X, bo, part0, 1024, 512, 256, 768, 1.0f, 0,
      786432LL, 131072LL, 524288LL, 32);
    stats_reduce<<<1, 1024, 0, stream>>>(part0, st0);

    // ---- Conv module: X += conv(X); refresh Xb ----
    conv_kernel<<<16384, 512, 0, stream>>>(X, Xb, st0, ln1_g, ln1_b, pw1_w, pw1_b,
                                           dw1_w, dw1_b, dw2_w, dw2_b,
                                           bn_g, bn_b, bn_m, bn_v, pw2_w, pw2_b);

    // ---- LFFN2: X = X + 0.5 * (swish(x@W1) @ W2), fused stats ----
    G(Xb, W1t_l2, nullptr, H, nullptr, nullptr, nullptr, 32768, 1024, 512, 512, 1.0f, 1, 0, 0, 0, 1);
    G(H, W2t_l2, X, nullptr, X, nullptr, part1, 32768, 512, 1024, 1024, 0.5f, 0, 0, 0, 0, 1);
    stats_reduce<<<1, 1024, 0, stream>>>(part1, st1);

    // ---- Final LN + residual ----
    final_kernel<<<16384, 256, 0, stream>>>(inp, X, st1, lnf_g, lnf_b, (float*)d_out);
}